// Round 4
// baseline (2470.328 us; speedup 1.0000x reference)
//
#include <hip/hip_runtime.h>
#include <hip/hip_bf16.h>

typedef __hip_bfloat16 bf16;

#define B_ROWS 32768

__device__ __forceinline__ float to_f(float x) { return x; }
__device__ __forceinline__ float to_f(bf16 x) { return __bfloat162float(x); }

// ---------------------------------------------------------------------------
// Generic tiled GEMM: out[M,N] = act(A[M,K] @ W[K,N] + bias[N])
// A: fp32 (d_in / d_out tensors) or bf16 (ws intermediates), row-major (lda).
// W: fp32 [K,N] row-major. bias: fp32[N] (nullable).
// outf: fp32 output (nullable, ldof). outb: bf16 output (nullable, ldob).
// ACT: 0 none, 1 relu, 2 sigmoid
// BM=64, BN=64, BK=16, 256 threads, 4x4 microtile. M must be multiple of 64.
// ---------------------------------------------------------------------------
template <typename TA, int ACT>
__global__ __launch_bounds__(256) void gemm_kernel(
    const TA* __restrict__ A, int lda,
    const float* __restrict__ W,
    const float* __restrict__ bias,
    float* __restrict__ outf, int ldof,
    bf16* __restrict__ outb, int ldob,
    int M, int N, int K)
{
    const int BM = 64, BN = 64, BK = 16;
    __shared__ float As[BK][BM];
    __shared__ float Ws[BK][BN];

    const int tid = threadIdx.x;
    const int m0 = blockIdx.y * BM;
    const int n0 = blockIdx.x * BN;
    const int tx = tid & 15;        // 0..15 -> n
    const int ty = tid >> 4;        // 0..15 -> m

    const int arow = tid >> 2;          // 0..63
    const int acol = (tid & 3) * 4;     // 0,4,8,12
    const int wk = tid >> 4;            // 0..15
    const int wn = (tid & 15) * 4;      // 0..60

    float acc[4][4] = {};

    for (int k0 = 0; k0 < K; k0 += BK) {
#pragma unroll
        for (int i = 0; i < 4; ++i) {
            int k = k0 + acol + i;
            float v = 0.f;
            if (k < K) v = to_f(A[(size_t)(m0 + arow) * lda + k]);
            As[acol + i][arow] = v;
        }
#pragma unroll
        for (int i = 0; i < 4; ++i) {
            int k = k0 + wk;
            int n = n0 + wn + i;
            float v = 0.f;
            if (k < K && n < N) v = W[(size_t)k * N + n];
            Ws[wk][wn + i] = v;
        }
        __syncthreads();
#pragma unroll
        for (int kk = 0; kk < BK; ++kk) {
            float4 a4 = *(const float4*)&As[kk][ty * 4];
            float4 b4 = *(const float4*)&Ws[kk][tx * 4];
            float a[4] = {a4.x, a4.y, a4.z, a4.w};
            float bv[4] = {b4.x, b4.y, b4.z, b4.w};
#pragma unroll
            for (int i = 0; i < 4; ++i)
#pragma unroll
                for (int j = 0; j < 4; ++j)
                    acc[i][j] = fmaf(a[i], bv[j], acc[i][j]);
        }
        __syncthreads();
    }

#pragma unroll
    for (int j = 0; j < 4; ++j) {
        int n = n0 + tx * 4 + j;
        if (n >= N) continue;
        float bb = bias ? bias[n] : 0.f;
#pragma unroll
        for (int i = 0; i < 4; ++i) {
            int m = m0 + ty * 4 + i;
            float v = acc[i][j] + bb;
            if (ACT == 1) v = fmaxf(v, 0.f);
            if (ACT == 2) v = 1.f / (1.f + __expf(-v));
            if (outf) outf[(size_t)m * ldof + n] = v;
            if (outb) outb[(size_t)m * ldob + n] = __float2bfloat16(v);
        }
    }
}

// ---------------------------------------------------------------------------
// Attention over seq-len 2, 4 heads x 64 dims, for a chunk of NB samples.
// qkv: [NB, 2, 768] bf16 (per position q|k|v). ctxm: [NB, 256] bf16 = mean
// over the two query positions of softmax(q k^T / 8) v.
// One wave per (sample, head); block 256 = 1 sample.
// ---------------------------------------------------------------------------
__global__ __launch_bounds__(256) void attn_kernel(
    const bf16* __restrict__ qkv, bf16* __restrict__ ctxm)
{
    const int b = blockIdx.x;
    const int lane = threadIdx.x & 63;
    const bf16* base = qkv + (size_t)b * 1536;
    const int o = (threadIdx.x >> 6) * 64 + lane;

    float q0 = to_f(base[o]),       k0 = to_f(base[256 + o]),       v0 = to_f(base[512 + o]);
    float q1 = to_f(base[768 + o]), k1 = to_f(base[768 + 256 + o]), v1 = to_f(base[768 + 512 + o]);

    float s00 = q0 * k0, s01 = q0 * k1, s10 = q1 * k0, s11 = q1 * k1;
#pragma unroll
    for (int off = 32; off; off >>= 1) {
        s00 += __shfl_xor(s00, off);
        s01 += __shfl_xor(s01, off);
        s10 += __shfl_xor(s10, off);
        s11 += __shfl_xor(s11, off);
    }
    const float sc = 0.125f;  // 1/sqrt(64)
    s00 *= sc; s01 *= sc; s10 *= sc; s11 *= sc;

    float m0 = fmaxf(s00, s01);
    float e00 = __expf(s00 - m0), e01 = __expf(s01 - m0);
    float r0 = 1.f / (e00 + e01);
    float m1 = fmaxf(s10, s11);
    float e10 = __expf(s10 - m1), e11 = __expf(s11 - m1);
    float r1 = 1.f / (e10 + e11);

    float c0 = e00 * r0 * v0 + e01 * r0 * v1;
    float c1 = e10 * r1 * v0 + e11 * r1 * v1;
    ctxm[(size_t)b * 256 + o] = __float2bfloat16(0.5f * (c0 + c1));
}

// ---------------------------------------------------------------------------
// Row softmax over 372 genus logits (bf16 in -> fp32 out). One wave per row.
// ---------------------------------------------------------------------------
__global__ __launch_bounds__(64) void softmax372_kernel(
    const bf16* __restrict__ in, float* __restrict__ outf)
{
    const int b = blockIdx.x;
    const int lane = threadIdx.x;
    const bf16* row = in + (size_t)b * 372;

    float v[6];
    float mx = -1e30f;
#pragma unroll
    for (int i = 0; i < 6; ++i) {
        int idx = lane + i * 64;
        v[i] = (idx < 372) ? to_f(row[idx]) : -1e30f;
        mx = fmaxf(mx, v[i]);
    }
#pragma unroll
    for (int off = 32; off; off >>= 1) mx = fmaxf(mx, __shfl_xor(mx, off));

    float s = 0.f;
#pragma unroll
    for (int i = 0; i < 6; ++i) {
        int idx = lane + i * 64;
        if (idx < 372) { v[i] = __expf(v[i] - mx); s += v[i]; }
    }
#pragma unroll
    for (int off = 32; off; off >>= 1) s += __shfl_xor(s, off);
    float r = 1.f / s;

#pragma unroll
    for (int i = 0; i < 6; ++i) {
        int idx = lane + i * 64;
        if (idx < 372) outf[(size_t)b * 372 + idx] = v[i] * r;
    }
}

// ---------------------------------------------------------------------------
// species[b,s] = genus[b, sg[s]] * local[b, sl[s]]  (fp32 in/out)
// ---------------------------------------------------------------------------
__global__ __launch_bounds__(256) void species_kernel(
    const float* __restrict__ g, const float* __restrict__ ll,
    const int* __restrict__ sg, const int* __restrict__ sl,
    float* __restrict__ out)
{
    const int s = blockIdx.x * 256 + threadIdx.x;
    const int b = blockIdx.y;
    if (s < 1050) {
        out[(size_t)b * 1050 + s] =
            g[(size_t)b * 372 + sg[s]] * ll[(size_t)b * 23 + sl[s]];
    }
}

extern "C" void kernel_launch(void* const* d_in, const int* in_sizes, int n_in,
                              void* d_out, int out_size, void* d_ws, size_t ws_size,
                              hipStream_t stream)
{
    const int B = B_ROWS;
    // Inputs fp32 (reference dtypes); output buffer fp32.
    const float* dna   = (const float*)d_in[0];
    const float* img   = (const float*)d_in[1];
    const float* W_dna = (const float*)d_in[2];  const float* b_dna = (const float*)d_in[3];
    const float* W_img = (const float*)d_in[4];  const float* b_img = (const float*)d_in[5];
    const float* W_qkv = (const float*)d_in[6];  const float* b_qkv = (const float*)d_in[7];
    const float* W_o   = (const float*)d_in[8];  const float* b_o   = (const float*)d_in[9];
    const float* W_f1  = (const float*)d_in[10]; const float* b_f1  = (const float*)d_in[11];
    const float* W_f2  = (const float*)d_in[12]; const float* b_f2  = (const float*)d_in[13];
    const float* W_d1  = (const float*)d_in[14]; const float* b_d1  = (const float*)d_in[15];
    const float* W_d2  = (const float*)d_in[16]; const float* b_d2  = (const float*)d_in[17];
    const float* W_fp  = (const float*)d_in[18]; const float* b_fp  = (const float*)d_in[19];
    const float* W_ge  = (const float*)d_in[20]; const float* b_ge  = (const float*)d_in[21];
    const float* W_s1  = (const float*)d_in[22]; const float* b_s1  = (const float*)d_in[23];
    const float* W_s2  = (const float*)d_in[24]; const float* b_s2  = (const float*)d_in[25];
    const int*   sg    = (const int*)d_in[26];
    const int*   sl    = (const int*)d_in[27];

    // bf16 workspace, peak B*1536 elems = 96 MiB.
    bf16* ws = (bf16*)d_ws;
    bf16* seq  = ws;                        // [B, 2, 256] = [2B,256]
    bf16* qkvc = ws + (size_t)B * 512;      // [B/2, 2, 768] per-chunk (2 chunks)
    bf16* ctxm = ws + (size_t)B * 1280;     // [B,256]
    bf16* t1   = ws;                        // [B,256]   (seq dead)
    bf16* t2   = ws + (size_t)B * 256;      // [B,256]
    bf16* h1   = ws + (size_t)B * 512;      // [B,744]   (qkvc dead)
    bf16* g    = ws;                        // [B,372]   (t1/t2 dead)
    bf16* gf   = ws + (size_t)B * 372;      // [B,192] = concat(ge, rf)
    bf16* sh   = ws + (size_t)B * 564;      // [B,64]

    float* out       = (float*)d_out;
    float* o_species = out;                          // [B,1050]
    float* o_local   = out + (size_t)B * 1050;       // [B,23]
    float* o_genus   = out + (size_t)B * 1073;       // [B,372]
    float* o_fused   = out + (size_t)B * 1445;       // [B,256]
    float* o_red     = out + (size_t)B * 1701;       // [B,128]

    dim3 blk(256);
#define GRID(M, N) dim3(((N) + 63) / 64, (M) / 64)
#define NOF (float*)nullptr, 0
#define NOB (bf16*)nullptr, 0

    // dna_proj / img_proj -> seq [B,2,256]
    gemm_kernel<float, 0><<<GRID(B, 256), blk, 0, stream>>>(
        dna, 768, W_dna, b_dna, NOF, seq, 512, B, 256, 768);
    gemm_kernel<float, 0><<<GRID(B, 256), blk, 0, stream>>>(
        img, 512, W_img, b_img, NOF, seq + 256, 512, B, 256, 512);
    // qkv + attention, 2 chunks of B/2 samples (B rows each of the [2B,768] GEMM)
    for (int c = 0; c < 2; ++c) {
        gemm_kernel<bf16, 0><<<GRID(B, 768), blk, 0, stream>>>(
            seq + (size_t)c * B * 256, 256, W_qkv, b_qkv, NOF, qkvc, 768, B, 768, 256);
        attn_kernel<<<B / 2, 256, 0, stream>>>(qkvc, ctxm + (size_t)c * (B / 2) * 256);
    }
    // t1 = ctxm @ W_o + b_o  (mean folded before W_o)
    gemm_kernel<bf16, 0><<<GRID(B, 256), blk, 0, stream>>>(
        ctxm, 256, W_o, b_o, NOF, t1, 256, B, 256, 256);
    // t2 = relu(t1 @ W_f1 + b_f1)
    gemm_kernel<bf16, 1><<<GRID(B, 256), blk, 0, stream>>>(
        t1, 256, W_f1, b_f1, NOF, t2, 256, B, 256, 256);
    // fused = t2 @ W_f2 + b_f2 -> output #4 (fp32; re-read from d_out below)
    gemm_kernel<bf16, 0><<<GRID(B, 256), blk, 0, stream>>>(
        t2, 256, W_f2, b_f2, o_fused, 256, NOB, B, 256, 256);
    // h1 = sigmoid(fused @ W_d1 + b_d1)  [B,744]
    gemm_kernel<float, 2><<<GRID(B, 744), blk, 0, stream>>>(
        o_fused, 256, W_d1, b_d1, NOF, h1, 744, B, 744, 256);
    // genus logits (pre-softmax) [B,372]
    gemm_kernel<bf16, 0><<<GRID(B, 372), blk, 0, stream>>>(
        h1, 744, W_d2, b_d2, NOF, g, 372, B, 372, 744);
    // genus softmax -> output #3 (fp32; downstream input)
    softmax372_kernel<<<B, 64, 0, stream>>>(g, o_genus);
    // genus_emb = genus @ W_ge + b_ge -> gf[:,0:64]
    gemm_kernel<float, 0><<<GRID(B, 64), blk, 0, stream>>>(
        o_genus, 372, W_ge, b_ge, NOF, gf, 192, B, 64, 372);
    // reduced_fused = fused @ W_fp + b_fp -> output #5 (fp32) and gf[:,64:192]
    gemm_kernel<float, 0><<<GRID(B, 128), blk, 0, stream>>>(
        o_fused, 256, W_fp, b_fp, o_red, 128, gf + 64, 192, B, 128, 256);
    // sh = sigmoid(gf @ W_s1 + b_s1)  [B,64]
    gemm_kernel<bf16, 2><<<GRID(B, 64), blk, 0, stream>>>(
        gf, 192, W_s1, b_s1, NOF, sh, 64, B, 64, 192);
    // local_logits = sh @ W_s2 + b_s2  [B,23] -> output #2 (fp32)
    gemm_kernel<bf16, 0><<<GRID(B, 23), blk, 0, stream>>>(
        sh, 64, W_s2, b_s2, o_local, 23, NOB, B, 23, 64);
    // species -> output #1 (fp32)
    species_kernel<<<dim3(5, B), blk, 0, stream>>>(o_genus, o_local, sg, sl, o_species);
#undef GRID
#undef NOF
#undef NOB
}